// Round 14
// baseline (609.779 us; speedup 1.0000x reference)
//
#include <hip/hip_runtime.h>

// Bidirectional GRU (Keras reset_after) B=32,T=128,E=512,U=1024.
// embed-cast -> fused weight transpose -> x_proj GEMM -> persistent recurrent
// kernel (64 WGs; epoch-tagged self-validating h exchange over sc0sc1,
// two-phase gate, LDS-only barriers) with ONE new delta: double-buffered LDS
// partials -> SINGLE barrier per step (tail barrier deleted) -> y merge.

using u16 = unsigned short;
using u32 = unsigned int;
typedef __attribute__((ext_vector_type(8))) short bfx8;
typedef __attribute__((ext_vector_type(4))) float f32x4;
typedef __attribute__((ext_vector_type(4))) u32 u32x4;
typedef __attribute__((ext_vector_type(4))) u16 u16x4;

#define B_ 32
#define T_ 128
#define E_ 512
#define U_ 1024
#define NG 3072
#define M_ 4096
#define YN 4194304
// Hx geometry: per dir, 3 rotating buffers; each [256 grp][32 b][16B]
// unit = {bf16 h[4g..4g+3] for row b (8B), u32 epoch tag, u32 tag copy}
#define ROTB 131072
#define HXD  393216

__device__ __forceinline__ float bf2f(u16 u) {
  union { u32 i; float f; } v; v.i = (u32)u << 16; return v.f;
}
__device__ __forceinline__ u16 f2bf(float f) {
  union { float f; u32 i; } v; v.f = f;
  u32 r = v.i + 0x7FFFu + ((v.i >> 16) & 1u);
  return (u16)(r >> 16);
}
__device__ __forceinline__ float sigm(float x) { return 1.0f / (1.0f + __expf(-x)); }
__device__ __forceinline__ float ftanh(float x) {
  float e = __expf(2.f * x);          // saturation-safe
  return 1.f - 2.f / (e + 1.f);
}

// barrier that drains ONLY LDS (lgkmcnt), leaving vmem loads/stores in flight.
#define BAR_LDS() do { \
  asm volatile("s_waitcnt lgkmcnt(0)\n\ts_barrier" ::: "memory"); \
  __builtin_amdgcn_sched_barrier(0); \
} while (0)

__device__ __forceinline__ void load_lds16(const void* g, void* l) {
  __builtin_amdgcn_global_load_lds(
      (const __attribute__((address_space(1))) u32*)g,
      (__attribute__((address_space(3))) u32*)l, 16, 0, 0);
}

// ---------------- P1: embedding gather + cast ----------------
__global__ __launch_bounds__(256) void k_embed(const int* __restrict__ tok,
                                               const float* __restrict__ emb,
                                               u16* __restrict__ X) {
  int idx = blockIdx.x * 256 + threadIdx.x;
  int m = idx >> 6, k8 = (idx & 63) << 3;
  int b = m & 31, t = m >> 5;
  int tk = tok[b * T_ + t];
  const float* s = emb + (size_t)tk * E_ + k8;
  float4 v0 = *(const float4*)s, v1 = *(const float4*)(s + 4);
  bfx8 r;
  r[0]=(short)f2bf(v0.x); r[1]=(short)f2bf(v0.y); r[2]=(short)f2bf(v0.z); r[3]=(short)f2bf(v0.w);
  r[4]=(short)f2bf(v1.x); r[5]=(short)f2bf(v1.y); r[6]=(short)f2bf(v1.z); r[7]=(short)f2bf(v1.w);
  *(bfx8*)(X + (size_t)m * E_ + k8) = r;
}

// ---------------- P2: fused transpose/cast of all 4 weight matrices ----------------
__global__ void k_transpose_all(const float* __restrict__ kf, const float* __restrict__ kb,
                                const float* __restrict__ rkf, const float* __restrict__ rkb,
                                u16* __restrict__ WT, u16* __restrict__ RW) {
  __shared__ float tile[32][33];
  const int z = blockIdx.z;
  const float* in; u16* outp; int K, remap, bx;
  if (blockIdx.x < 16) { in = z ? kb : kf;   outp = WT + (size_t)z * 3072 * 512;  K = 512;  remap = 0; bx = blockIdx.x; }
  else                 { in = z ? rkb : rkf; outp = RW + (size_t)z * 3072 * 1024; K = 1024; remap = 1; bx = blockIdx.x - 16; }
  int k0 = bx * 32, n0 = blockIdx.y * 32;
  int tx = threadIdx.x, ty = threadIdx.y;
  for (int j = ty; j < 32; j += 8) tile[j][tx] = in[(size_t)(k0 + j) * NG + n0 + tx];
  __syncthreads();
  for (int j = ty; j < 32; j += 8) {
    int n = n0 + j;
    int row = remap ? ((((n & 1023) >> 5) * 96) + ((n >> 10) << 5) + (n & 31)) : n;
    outp[(size_t)row * K + k0 + tx] = f2bf(tile[tx][j]);
  }
}

// ---------------- G: x_proj GEMM ----------------
__global__ __launch_bounds__(256) void k_xproj(const u16* __restrict__ X,
                                               const u16* __restrict__ WT,
                                               const float* __restrict__ biasF,
                                               const float* __restrict__ biasB,
                                               u16* __restrict__ XP) {
  const int n0 = blockIdx.x * 128, m0 = blockIdx.y * 128, dir = blockIdx.z;
  const float* bias = dir ? biasB : biasF;
  const u16* Wd = WT + (size_t)dir * NG * E_;
  __shared__ __align__(16) u16 As[128 * 64];
  __shared__ __align__(16) u16 Bs[128 * 64];
  const int tid = threadIdx.x;
  const int wave = tid >> 6, lane = tid & 63;
  const int moff = (wave >> 1) * 64, noff = (wave & 1) * 64;
  const int l15 = lane & 15, l4 = lane >> 4;
  f32x4 acc[4][4] = {};
  for (int kt = 0; kt < 8; ++kt) {
    int k0 = kt * 64;
#pragma unroll
    for (int j = 0; j < 4; ++j) {
      int o = j * 4096 + tid * 16;
      int row = o >> 7;
      int kk = (((o & 127) ^ ((row & 7) << 4)) >> 1);
      load_lds16(X  + (size_t)(m0 + row) * E_ + k0 + kk, (char*)As + o);
      load_lds16(Wd + (size_t)(n0 + row) * E_ + k0 + kk, (char*)Bs + o);
    }
    __syncthreads();
#pragma unroll
    for (int Ks = 0; Ks < 2; ++Ks) {
      bfx8 a[4], b[4];
#pragma unroll
      for (int Mt = 0; Mt < 4; ++Mt) {
        int ra = moff + Mt * 16 + l15;
        int ba = (ra << 7) + ((Ks * 32 + l4 * 8) << 1);
        ba ^= (ra & 7) << 4;
        a[Mt] = *(const bfx8*)((const char*)As + ba);
      }
#pragma unroll
      for (int Nt = 0; Nt < 4; ++Nt) {
        int rb = noff + Nt * 16 + l15;
        int bb2 = (rb << 7) + ((Ks * 32 + l4 * 8) << 1);
        bb2 ^= (rb & 7) << 4;
        b[Nt] = *(const bfx8*)((const char*)Bs + bb2);
      }
#pragma unroll
      for (int Mt = 0; Mt < 4; ++Mt)
#pragma unroll
        for (int Nt = 0; Nt < 4; ++Nt)
          acc[Mt][Nt] = __builtin_amdgcn_mfma_f32_16x16x32_bf16(a[Mt], b[Nt], acc[Mt][Nt], 0, 0, 0);
    }
    __syncthreads();
  }
  float bv[4];
#pragma unroll
  for (int Nt = 0; Nt < 4; ++Nt) bv[Nt] = bias[n0 + noff + Nt * 16 + l15];
#pragma unroll
  for (int Mt = 0; Mt < 4; ++Mt)
#pragma unroll
    for (int Nt = 0; Nt < 4; ++Nt)
#pragma unroll
      for (int r = 0; r < 4; ++r) {
        int m = m0 + moff + Mt * 16 + l4 * 4 + r;
        int n = n0 + noff + Nt * 16 + l15;
        XP[((size_t)dir * M_ + m) * NG + n] = f2bf(acc[Mt][Nt][r] + bv[Nt]);
      }
}

// ---------------- R: persistent recurrent kernel ----------------
// 64 WGs = 2 dirs x 32 slices. Epoch-tagged 16B units; two-phase gate (loads
// issued+consumed inside the gate block); LDS-only barriers; double-buffered
// pl -> SINGLE barrier per step. 3-buffer rotation proof unchanged.
#define GISS(Ks) { \
  const char* a_ = rbase + offb + (Ks) * 4096; \
  asm volatile("global_load_dwordx4 %0, %1, off sc0 sc1"             : "=v"(L[0][Ks])  : "v"(a_)); \
  asm volatile("global_load_dwordx4 %0, %1, off offset:256 sc0 sc1" : "=v"(L2[0][Ks]) : "v"(a_)); \
  asm volatile("global_load_dwordx4 %0, %1, off offset:512 sc0 sc1" : "=v"(L[1][Ks])  : "v"(a_)); \
  asm volatile("global_load_dwordx4 %0, %1, off offset:768 sc0 sc1" : "=v"(L2[1][Ks]) : "v"(a_)); }

__global__ __launch_bounds__(256, 1) void k_gru(
    const u16* __restrict__ RW,
    u16* __restrict__ XP,
    const float* __restrict__ bf_, const float* __restrict__ bb_,
    char* __restrict__ Hx,
    float* __restrict__ out) {
  const int tid = threadIdx.x;
  const int wave = tid >> 6, lane = tid & 63;
  const int wg = blockIdx.x;
  const int dir = wg & 1, slice = wg >> 1;
  const int u0 = slice * 32;
  const float* b1p = (dir ? bb_ : bf_) + NG;
  const u16* wbase = RW + (size_t)dir * NG * U_ + (size_t)slice * 96 * U_;
  u16* xpd = XP + (size_t)dir * M_ * NG;
  char* hxd = Hx + (size_t)dir * HXD;
  __shared__ float pl[2][4][32][97];               // double-buffered partials

  const int l15 = lane & 15, l4 = lane >> 4;

  // preload this wave's 48 weight frags — resident all 128 steps
  bfx8 wf[6][8];
#pragma unroll
  for (int Nt = 0; Nt < 6; ++Nt)
#pragma unroll
    for (int Ks = 0; Ks < 8; ++Ks) {
      int c = Nt * 16 + l15;
      int k = wave * 256 + Ks * 32 + l4 * 8;
      wf[Nt][Ks] = *(const bfx8*)(wbase + (size_t)c * U_ + k);
    }

  // epilogue mapping: thread owns (b=eb, cols u0+uu..u0+uu+3)
  const int eb = tid & 31;
  const int ug = tid >> 5;
  const int uu = ug * 4;
  float b1[3][4];
#pragma unroll
  for (int g = 0; g < 3; ++g)
#pragma unroll
    for (int j = 0; j < 4; ++j) b1[g][j] = b1p[g * U_ + u0 + uu + j];
  float hreg[4] = {0.f, 0.f, 0.f, 0.f};

  const int offb = wave * 32768 + l4 * 1024 + l15 * 16;          // consumer bulk base
  const int soff = (slice * 8 + ug) * 512 + eb * 16;             // producer unit

  // xc holds CURRENT step's x; loaded up-front for step 0
  u16x4 xc[3];
  {
    int t0 = dir ? 127 : 0;
    const u16* xr = xpd + (size_t)(t0 * 32 + eb) * NG + u0 + uu;
#pragma unroll
    for (int g = 0; g < 3; ++g) xc[g] = *(const u16x4*)(xr + g * U_);
  }

  int rl = 0, rs = 1;                              // rl = e%3, rs = (e+1)%3
  int cur = 0;                                     // pl buffer selector
  for (int e = 0; e < 128; ++e) {
    f32x4 acc[2][6] = {};
    u16x4 xn[3] = {xc[0], xc[1], xc[2]};           // next-step x (default keep)
    if (e > 0) {
      const u32 etag = (u32)e;
      char* rbase = hxd + rl * ROTB;
      u32x4 L[2][8], L2[2][8];
      // issue ALL 32 unit loads: group A (Ks 0-3) oldest, group B (Ks 4-7)
      GISS(0) GISS(1) GISS(2) GISS(3)
      GISS(4) GISS(5) GISS(6) GISS(7)
      // ---- phase A: vmcnt(16) -> in-order retirement means A retired ----
      {
        asm volatile("s_waitcnt vmcnt(16)");
        int guard = 0;
        while (1) {
          u32 bad = 0;
#pragma unroll
          for (int Ks = 0; Ks < 4; ++Ks) {
            asm volatile("" : "+v"(L[0][Ks]), "+v"(L2[0][Ks]), "+v"(L[1][Ks]), "+v"(L2[1][Ks]));
            bad |= (L[0][Ks].z ^ etag) | (L2[0][Ks].z ^ etag) |
                   (L[1][Ks].z ^ etag) | (L2[1][Ks].z ^ etag);
          }
          if (__all((int)(bad == 0))) break;
          if (++guard > (1 << 18)) break;          // fail visibly, never hang
          GISS(0) GISS(1) GISS(2) GISS(3)
          asm volatile("s_waitcnt vmcnt(0)");
        }
      }
      bfx8 afA[2][4];
#pragma unroll
      for (int Ks = 0; Ks < 4; ++Ks) {
        u32x4 f0 = {L[0][Ks].x, L[0][Ks].y, L[1][Ks].x, L[1][Ks].y};
        u32x4 f1 = {L2[0][Ks].x, L2[0][Ks].y, L2[1][Ks].x, L2[1][Ks].y};
        afA[0][Ks] = __builtin_bit_cast(bfx8, f0);
        afA[1][Ks] = __builtin_bit_cast(bfx8, f1);
      }
      __builtin_amdgcn_sched_barrier(0);
#pragma unroll
      for (int Ks = 0; Ks < 4; ++Ks)
#pragma unroll
        for (int Mt = 0; Mt < 2; ++Mt)
#pragma unroll
          for (int Nt = 0; Nt < 6; ++Nt)
            acc[Mt][Nt] = __builtin_amdgcn_mfma_f32_16x16x32_bf16(afA[Mt][Ks], wf[Nt][Ks],
                                                                  acc[Mt][Nt], 0, 0, 0);
      // ---- phase B: drain rest, validate chunks 4-7 ----
      {
        asm volatile("s_waitcnt vmcnt(0)");
        int guard = 0;
        while (1) {
          u32 bad = 0;
#pragma unroll
          for (int Ks = 4; Ks < 8; ++Ks) {
            asm volatile("" : "+v"(L[0][Ks]), "+v"(L2[0][Ks]), "+v"(L[1][Ks]), "+v"(L2[1][Ks]));
            bad |= (L[0][Ks].z ^ etag) | (L2[0][Ks].z ^ etag) |
                   (L[1][Ks].z ^ etag) | (L2[1][Ks].z ^ etag);
          }
          if (__all((int)(bad == 0))) break;
          if (++guard > (1 << 18)) break;          // fail visibly, never hang
          GISS(4) GISS(5) GISS(6) GISS(7)
          asm volatile("s_waitcnt vmcnt(0)");
        }
      }
      bfx8 afB[2][4];
#pragma unroll
      for (int Ks = 4; Ks < 8; ++Ks) {
        u32x4 f0 = {L[0][Ks].x, L[0][Ks].y, L[1][Ks].x, L[1][Ks].y};
        u32x4 f1 = {L2[0][Ks].x, L2[0][Ks].y, L2[1][Ks].x, L2[1][Ks].y};
        afB[0][Ks - 4] = __builtin_bit_cast(bfx8, f0);
        afB[1][Ks - 4] = __builtin_bit_cast(bfx8, f1);
      }
      // prefetch next step's x (shadowed by the B MFMA + dump/reduce phase)
      if (e < 127) {
        int tn = dir ? (126 - e) : (e + 1);
        const u16* xr = xpd + (size_t)(tn * 32 + eb) * NG + u0 + uu;
#pragma unroll
        for (int g = 0; g < 3; ++g) xn[g] = *(const u16x4*)(xr + g * U_);
      }
      __builtin_amdgcn_sched_barrier(0);
#pragma unroll
      for (int Ks = 0; Ks < 4; ++Ks)
#pragma unroll
        for (int Mt = 0; Mt < 2; ++Mt)
#pragma unroll
          for (int Nt = 0; Nt < 6; ++Nt)
            acc[Mt][Nt] = __builtin_amdgcn_mfma_f32_16x16x32_bf16(afB[Mt][Ks], wf[Nt][Ks + 4],
                                                                  acc[Mt][Nt], 0, 0, 0);
    } else {
      // e==0: rec contribution is zero; prefetch x for step 1
      int tn = dir ? 126 : 1;
      const u16* xr = xpd + (size_t)(tn * 32 + eb) * NG + u0 + uu;
#pragma unroll
      for (int g = 0; g < 3; ++g) xn[g] = *(const u16x4*)(xr + g * U_);
    }
    // dump partials into pl[cur]: C/D layout col=lane&15, row=(lane>>4)*4+r
#pragma unroll
    for (int Mt = 0; Mt < 2; ++Mt)
#pragma unroll
      for (int Nt = 0; Nt < 6; ++Nt)
#pragma unroll
        for (int r = 0; r < 4; ++r)
          pl[cur][wave][Mt * 16 + l4 * 4 + r][Nt * 16 + l15] = acc[Mt][Nt][r];
    BAR_LDS();    // the ONLY barrier per step: all 4 waves dumped pl[cur].
                  // Next epoch dumps go to pl[cur^1] -> no tail barrier needed.
    // reduce K-quarters + gates; publish FIRST, then deferred y (pre-update h)
    float hold[4];
#pragma unroll
    for (int j = 0; j < 4; ++j) hold[j] = hreg[j];
#pragma unroll
    for (int j = 0; j < 4; ++j) {
      int c = uu + j;
      float rz = pl[cur][0][eb][c]      + pl[cur][1][eb][c]      + pl[cur][2][eb][c]      + pl[cur][3][eb][c];
      float rr = pl[cur][0][eb][32 + c] + pl[cur][1][eb][32 + c] + pl[cur][2][eb][32 + c] + pl[cur][3][eb][32 + c];
      float rh = pl[cur][0][eb][64 + c] + pl[cur][1][eb][64 + c] + pl[cur][2][eb][64 + c] + pl[cur][3][eb][64 + c];
      float z  = sigm(bf2f(xc[0][j]) + rz + b1[0][j]);
      float r  = sigm(bf2f(xc[1][j]) + rr + b1[1][j]);
      float hh = ftanh(bf2f(xc[2][j]) + r * (rh + b1[2][j]));
      hreg[j] = z * hreg[j] + (1.f - z) * hh;
    }
    {
      u32 p01 = (u32)f2bf(hreg[0]) | ((u32)f2bf(hreg[1]) << 16);
      u32 p23 = (u32)f2bf(hreg[2]) | ((u32)f2bf(hreg[3]) << 16);
      u32x4 sv; sv.x = p01; sv.y = p23; sv.z = (u32)(e + 1); sv.w = (u32)(e + 1);
      char* sa = hxd + rs * ROTB + soff;
      asm volatile("global_store_dwordx4 %0, %1, off sc0 sc1" :: "v"(sa), "v"(sv));
    }
    // deferred y for epoch e-1. Safe: tag-e visibility data-depends on each
    // producer's epoch-(e-1) x loads (through its hreg chain) => every WG
    // consumed XP row t(e-1) before its tag e became visible.
    if (e > 0) {
      const int tp = dir ? (128 - e) : (e - 1);
      float* yrow = (float*)(xpd + (size_t)(tp * 32 + eb) * NG);
      *(float4*)(yrow + u0 + uu) = make_float4(hold[0], hold[1], hold[2], hold[3]);
    }
    xc[0] = xn[0]; xc[1] = xn[1]; xc[2] = xn[2];
    rl = rs; rs = (rs == 2) ? 0 : rs + 1;
    cur ^= 1;                                      // no tail barrier
  }
  // final: wait for all 32 slices' tag-128 (rot 2), then last y row + states
  {
    const char* pa = hxd + 2 * ROTB + ((lane & 31) * 8 + 7) * 512 + 31 * 16;
    int g = 0;
    while (1) {
      u32 tv = 128u;
      if (lane < 32) {
        u32x4 tvv;
        asm volatile("global_load_dwordx4 %0, %1, off sc0 sc1\n\ts_waitcnt vmcnt(0)"
                     : "=v"(tvv) : "v"(pa));
        tv = tvv.z;
      }
      if (__all((int)(tv == 128u))) break;
      if (++g > (1 << 22)) break;
      __builtin_amdgcn_s_sleep(1);
    }
    const int tl = dir ? 0 : 127;
    float* yrow = (float*)(xpd + (size_t)(tl * 32 + eb) * NG);
    *(float4*)(yrow + u0 + uu) = make_float4(hreg[0], hreg[1], hreg[2], hreg[3]);
    float* os = out + YN + (size_t)dir * (B_ * U_) + (size_t)eb * U_ + u0 + uu;
    *(float4*)os = make_float4(hreg[0], hreg[1], hreg[2], hreg[3]);
  }
}

// ---------------- M: y merge  out = yf + yb ----------------
__global__ __launch_bounds__(256) void k_merge(const u16* __restrict__ XP,
                                               float* __restrict__ out) {
  int idx = blockIdx.x * 256 + threadIdx.x;
  int u4 = (idx & 255) * 4;
  int m = idx >> 8;                            // t*32+b
  int t = m >> 5, b = m & 31;
  const float* yf = (const float*)(XP + (size_t)m * NG);
  const float* yb = (const float*)(XP + (size_t)(M_ + m) * NG);
  float4 a = *(const float4*)(yf + u4);
  float4 c = *(const float4*)(yb + u4);
  float4 o; o.x = a.x + c.x; o.y = a.y + c.y; o.z = a.z + c.z; o.w = a.w + c.w;
  *(float4*)(out + ((size_t)b * T_ + t) * U_ + u4) = o;
}

extern "C" void kernel_launch(void* const* d_in, const int* in_sizes, int n_in,
                              void* d_out, int out_size, void* d_ws, size_t ws_size,
                              hipStream_t stream) {
  const int*   tokens = (const int*)d_in[0];
  const float* emb    = (const float*)d_in[1];
  const float* kf     = (const float*)d_in[2];
  const float* rkf    = (const float*)d_in[3];
  const float* bf_    = (const float*)d_in[4];
  const float* kb     = (const float*)d_in[5];
  const float* rkb    = (const float*)d_in[6];
  const float* bb_    = (const float*)d_in[7];
  float* out = (float*)d_out;
  char* ws = (char*)d_ws;

  u16*  X  = (u16*)ws;                        // 4 MB
  u16*  WT = (u16*)(ws + 0x400000);           // 6 MB
  char* Hx = ws + 0x400000;                   // 768 KB (aliases WT; WT dead post-xproj)
  u16*  RW = (u16*)(ws + 0xA00000);           // 12 MB
  u16*  XP = (u16*)(ws + 0x1600000);          // 48 MB (y stashed in row heads)

  k_embed<<<1024, 256, 0, stream>>>(tokens, emb, X);
  k_transpose_all<<<dim3(48, 96, 2), dim3(32, 8), 0, stream>>>(kf, kb, rkf, rkb, WT, RW);
  k_xproj<<<dim3(24, 32, 2), 256, 0, stream>>>(X, WT, bf_, bb_, XP);
  hipMemsetAsync(Hx, 0, 2 * HXD, stream);
  k_gru<<<64, 256, 0, stream>>>(RW, XP, bf_, bb_, Hx, out);
  k_merge<<<4096, 256, 0, stream>>>(XP, out);
}

// Round 15
// 605.929 us; speedup vs baseline: 1.0064x; 1.0064x over previous
//
#include <hip/hip_runtime.h>

// Bidirectional GRU (Keras reset_after) B=32,T=128,E=512,U=1024.
// embed-cast -> fused weight transpose -> x_proj GEMM -> persistent recurrent
// kernel (64 WGs; epoch-tagged self-validating h exchange over sc0sc1,
// two-phase gate, LDS-only barriers) -> y merge.  [R13 configuration — best
// measured: total 592 us, k_gru 529 us]

using u16 = unsigned short;
using u32 = unsigned int;
typedef __attribute__((ext_vector_type(8))) short bfx8;
typedef __attribute__((ext_vector_type(4))) float f32x4;
typedef __attribute__((ext_vector_type(4))) u32 u32x4;
typedef __attribute__((ext_vector_type(4))) u16 u16x4;

#define B_ 32
#define T_ 128
#define E_ 512
#define U_ 1024
#define NG 3072
#define M_ 4096
#define YN 4194304
// Hx geometry: per dir, 3 rotating buffers; each [256 grp][32 b][16B]
// unit = {bf16 h[4g..4g+3] for row b (8B), u32 epoch tag, u32 tag copy}
#define ROTB 131072
#define HXD  393216

__device__ __forceinline__ float bf2f(u16 u) {
  union { u32 i; float f; } v; v.i = (u32)u << 16; return v.f;
}
__device__ __forceinline__ u16 f2bf(float f) {
  union { float f; u32 i; } v; v.f = f;
  u32 r = v.i + 0x7FFFu + ((v.i >> 16) & 1u);
  return (u16)(r >> 16);
}
__device__ __forceinline__ float sigm(float x) { return 1.0f / (1.0f + __expf(-x)); }
__device__ __forceinline__ float ftanh(float x) {
  float e = __expf(2.f * x);          // saturation-safe
  return 1.f - 2.f / (e + 1.f);
}

// barrier that drains ONLY LDS (lgkmcnt), leaving vmem loads/stores in flight.
// Safe here: barriers order only the pl dump/reduce; the h exchange is ordered
// by the tag protocol's data dependencies, not by barriers.
#define BAR_LDS() do { \
  asm volatile("s_waitcnt lgkmcnt(0)\n\ts_barrier" ::: "memory"); \
  __builtin_amdgcn_sched_barrier(0); \
} while (0)

__device__ __forceinline__ void load_lds16(const void* g, void* l) {
  __builtin_amdgcn_global_load_lds(
      (const __attribute__((address_space(1))) u32*)g,
      (__attribute__((address_space(3))) u32*)l, 16, 0, 0);
}

// ---------------- P1: embedding gather + cast ----------------
__global__ __launch_bounds__(256) void k_embed(const int* __restrict__ tok,
                                               const float* __restrict__ emb,
                                               u16* __restrict__ X) {
  int idx = blockIdx.x * 256 + threadIdx.x;
  int m = idx >> 6, k8 = (idx & 63) << 3;
  int b = m & 31, t = m >> 5;
  int tk = tok[b * T_ + t];
  const float* s = emb + (size_t)tk * E_ + k8;
  float4 v0 = *(const float4*)s, v1 = *(const float4*)(s + 4);
  bfx8 r;
  r[0]=(short)f2bf(v0.x); r[1]=(short)f2bf(v0.y); r[2]=(short)f2bf(v0.z); r[3]=(short)f2bf(v0.w);
  r[4]=(short)f2bf(v1.x); r[5]=(short)f2bf(v1.y); r[6]=(short)f2bf(v1.z); r[7]=(short)f2bf(v1.w);
  *(bfx8*)(X + (size_t)m * E_ + k8) = r;
}

// ---------------- P2: fused transpose/cast of all 4 weight matrices ----------------
__global__ void k_transpose_all(const float* __restrict__ kf, const float* __restrict__ kb,
                                const float* __restrict__ rkf, const float* __restrict__ rkb,
                                u16* __restrict__ WT, u16* __restrict__ RW) {
  __shared__ float tile[32][33];
  const int z = blockIdx.z;
  const float* in; u16* outp; int K, remap, bx;
  if (blockIdx.x < 16) { in = z ? kb : kf;   outp = WT + (size_t)z * 3072 * 512;  K = 512;  remap = 0; bx = blockIdx.x; }
  else                 { in = z ? rkb : rkf; outp = RW + (size_t)z * 3072 * 1024; K = 1024; remap = 1; bx = blockIdx.x - 16; }
  int k0 = bx * 32, n0 = blockIdx.y * 32;
  int tx = threadIdx.x, ty = threadIdx.y;
  for (int j = ty; j < 32; j += 8) tile[j][tx] = in[(size_t)(k0 + j) * NG + n0 + tx];
  __syncthreads();
  for (int j = ty; j < 32; j += 8) {
    int n = n0 + j;
    int row = remap ? ((((n & 1023) >> 5) * 96) + ((n >> 10) << 5) + (n & 31)) : n;
    outp[(size_t)row * K + k0 + tx] = f2bf(tile[tx][j]);
  }
}

// ---------------- G: x_proj GEMM ----------------
__global__ __launch_bounds__(256) void k_xproj(const u16* __restrict__ X,
                                               const u16* __restrict__ WT,
                                               const float* __restrict__ biasF,
                                               const float* __restrict__ biasB,
                                               u16* __restrict__ XP) {
  const int n0 = blockIdx.x * 128, m0 = blockIdx.y * 128, dir = blockIdx.z;
  const float* bias = dir ? biasB : biasF;
  const u16* Wd = WT + (size_t)dir * NG * E_;
  __shared__ __align__(16) u16 As[128 * 64];
  __shared__ __align__(16) u16 Bs[128 * 64];
  const int tid = threadIdx.x;
  const int wave = tid >> 6, lane = tid & 63;
  const int moff = (wave >> 1) * 64, noff = (wave & 1) * 64;
  const int l15 = lane & 15, l4 = lane >> 4;
  f32x4 acc[4][4] = {};
  for (int kt = 0; kt < 8; ++kt) {
    int k0 = kt * 64;
#pragma unroll
    for (int j = 0; j < 4; ++j) {
      int o = j * 4096 + tid * 16;
      int row = o >> 7;
      int kk = (((o & 127) ^ ((row & 7) << 4)) >> 1);
      load_lds16(X  + (size_t)(m0 + row) * E_ + k0 + kk, (char*)As + o);
      load_lds16(Wd + (size_t)(n0 + row) * E_ + k0 + kk, (char*)Bs + o);
    }
    __syncthreads();
#pragma unroll
    for (int Ks = 0; Ks < 2; ++Ks) {
      bfx8 a[4], b[4];
#pragma unroll
      for (int Mt = 0; Mt < 4; ++Mt) {
        int ra = moff + Mt * 16 + l15;
        int ba = (ra << 7) + ((Ks * 32 + l4 * 8) << 1);
        ba ^= (ra & 7) << 4;
        a[Mt] = *(const bfx8*)((const char*)As + ba);
      }
#pragma unroll
      for (int Nt = 0; Nt < 4; ++Nt) {
        int rb = noff + Nt * 16 + l15;
        int bb2 = (rb << 7) + ((Ks * 32 + l4 * 8) << 1);
        bb2 ^= (rb & 7) << 4;
        b[Nt] = *(const bfx8*)((const char*)Bs + bb2);
      }
#pragma unroll
      for (int Mt = 0; Mt < 4; ++Mt)
#pragma unroll
        for (int Nt = 0; Nt < 4; ++Nt)
          acc[Mt][Nt] = __builtin_amdgcn_mfma_f32_16x16x32_bf16(a[Mt], b[Nt], acc[Mt][Nt], 0, 0, 0);
    }
    __syncthreads();
  }
  float bv[4];
#pragma unroll
  for (int Nt = 0; Nt < 4; ++Nt) bv[Nt] = bias[n0 + noff + Nt * 16 + l15];
#pragma unroll
  for (int Mt = 0; Mt < 4; ++Mt)
#pragma unroll
    for (int Nt = 0; Nt < 4; ++Nt)
#pragma unroll
      for (int r = 0; r < 4; ++r) {
        int m = m0 + moff + Mt * 16 + l4 * 4 + r;
        int n = n0 + noff + Nt * 16 + l15;
        XP[((size_t)dir * M_ + m) * NG + n] = f2bf(acc[Mt][Nt][r] + bv[Nt]);
      }
}

// ---------------- R: persistent recurrent kernel ----------------
// 64 WGs = 2 dirs x 32 slices. Epoch-tagged 16B units; TWO-PHASE gate (loads
// issued and consumed INSIDE the gate block — asm load dests never live across
// barriers/back-edges). LDS-only barriers. 3-buffer rotation.
#define GISS(Ks) { \
  const char* a_ = rbase + offb + (Ks) * 4096; \
  asm volatile("global_load_dwordx4 %0, %1, off sc0 sc1"             : "=v"(L[0][Ks])  : "v"(a_)); \
  asm volatile("global_load_dwordx4 %0, %1, off offset:256 sc0 sc1" : "=v"(L2[0][Ks]) : "v"(a_)); \
  asm volatile("global_load_dwordx4 %0, %1, off offset:512 sc0 sc1" : "=v"(L[1][Ks])  : "v"(a_)); \
  asm volatile("global_load_dwordx4 %0, %1, off offset:768 sc0 sc1" : "=v"(L2[1][Ks]) : "v"(a_)); }

__global__ __launch_bounds__(256, 1) void k_gru(
    const u16* __restrict__ RW,
    u16* __restrict__ XP,
    const float* __restrict__ bf_, const float* __restrict__ bb_,
    char* __restrict__ Hx,
    float* __restrict__ out) {
  const int tid = threadIdx.x;
  const int wave = tid >> 6, lane = tid & 63;
  const int wg = blockIdx.x;
  const int dir = wg & 1, slice = wg >> 1;
  const int u0 = slice * 32;
  const float* b1p = (dir ? bb_ : bf_) + NG;
  const u16* wbase = RW + (size_t)dir * NG * U_ + (size_t)slice * 96 * U_;
  u16* xpd = XP + (size_t)dir * M_ * NG;
  char* hxd = Hx + (size_t)dir * HXD;
  __shared__ float pl[4][32][97];

  const int l15 = lane & 15, l4 = lane >> 4;

  // preload this wave's 48 weight frags — resident all 128 steps
  bfx8 wf[6][8];
#pragma unroll
  for (int Nt = 0; Nt < 6; ++Nt)
#pragma unroll
    for (int Ks = 0; Ks < 8; ++Ks) {
      int c = Nt * 16 + l15;
      int k = wave * 256 + Ks * 32 + l4 * 8;
      wf[Nt][Ks] = *(const bfx8*)(wbase + (size_t)c * U_ + k);
    }

  // epilogue mapping: thread owns (b=eb, cols u0+uu..u0+uu+3)
  const int eb = tid & 31;
  const int ug = tid >> 5;
  const int uu = ug * 4;
  float b1[3][4];
#pragma unroll
  for (int g = 0; g < 3; ++g)
#pragma unroll
    for (int j = 0; j < 4; ++j) b1[g][j] = b1p[g * U_ + u0 + uu + j];
  float hreg[4] = {0.f, 0.f, 0.f, 0.f};

  const int offb = wave * 32768 + l4 * 1024 + l15 * 16;          // consumer bulk base
  const int soff = (slice * 8 + ug) * 512 + eb * 16;             // producer unit

  // xc holds CURRENT step's x; loaded up-front for step 0
  u16x4 xc[3];
  {
    int t0 = dir ? 127 : 0;
    const u16* xr = xpd + (size_t)(t0 * 32 + eb) * NG + u0 + uu;
#pragma unroll
    for (int g = 0; g < 3; ++g) xc[g] = *(const u16x4*)(xr + g * U_);
  }

  int rl = 0, rs = 1;                              // rl = e%3, rs = (e+1)%3
  for (int e = 0; e < 128; ++e) {
    f32x4 acc[2][6] = {};
    u16x4 xn[3] = {xc[0], xc[1], xc[2]};           // next-step x (default keep)
    if (e > 0) {
      const u32 etag = (u32)e;
      char* rbase = hxd + rl * ROTB;
      u32x4 L[2][8], L2[2][8];
      // issue ALL 32 unit loads: group A (Ks 0-3) oldest, group B (Ks 4-7)
      GISS(0) GISS(1) GISS(2) GISS(3)
      GISS(4) GISS(5) GISS(6) GISS(7)
      // ---- phase A: vmcnt(16) -> in-order retirement means A retired ----
      {
        asm volatile("s_waitcnt vmcnt(16)");
        int guard = 0;
        while (1) {
          u32 bad = 0;
#pragma unroll
          for (int Ks = 0; Ks < 4; ++Ks) {
            asm volatile("" : "+v"(L[0][Ks]), "+v"(L2[0][Ks]), "+v"(L[1][Ks]), "+v"(L2[1][Ks]));
            bad |= (L[0][Ks].z ^ etag) | (L2[0][Ks].z ^ etag) |
                   (L[1][Ks].z ^ etag) | (L2[1][Ks].z ^ etag);
          }
          if (__all((int)(bad == 0))) break;
          if (++guard > (1 << 18)) break;          // fail visibly, never hang
          __builtin_amdgcn_s_sleep(1);
          GISS(0) GISS(1) GISS(2) GISS(3)
          asm volatile("s_waitcnt vmcnt(0)");
        }
      }
      bfx8 afA[2][4];
#pragma unroll
      for (int Ks = 0; Ks < 4; ++Ks) {
        u32x4 f0 = {L[0][Ks].x, L[0][Ks].y, L[1][Ks].x, L[1][Ks].y};
        u32x4 f1 = {L2[0][Ks].x, L2[0][Ks].y, L2[1][Ks].x, L2[1][Ks].y};
        afA[0][Ks] = __builtin_bit_cast(bfx8, f0);
        afA[1][Ks] = __builtin_bit_cast(bfx8, f1);
      }
      __builtin_amdgcn_sched_barrier(0);
#pragma unroll
      for (int Ks = 0; Ks < 4; ++Ks)
#pragma unroll
        for (int Mt = 0; Mt < 2; ++Mt)
#pragma unroll
          for (int Nt = 0; Nt < 6; ++Nt)
            acc[Mt][Nt] = __builtin_amdgcn_mfma_f32_16x16x32_bf16(afA[Mt][Ks], wf[Nt][Ks],
                                                                  acc[Mt][Nt], 0, 0, 0);
      // ---- phase B: drain rest, validate chunks 4-7 ----
      {
        asm volatile("s_waitcnt vmcnt(0)");
        int guard = 0;
        while (1) {
          u32 bad = 0;
#pragma unroll
          for (int Ks = 4; Ks < 8; ++Ks) {
            asm volatile("" : "+v"(L[0][Ks]), "+v"(L2[0][Ks]), "+v"(L[1][Ks]), "+v"(L2[1][Ks]));
            bad |= (L[0][Ks].z ^ etag) | (L2[0][Ks].z ^ etag) |
                   (L[1][Ks].z ^ etag) | (L2[1][Ks].z ^ etag);
          }
          if (__all((int)(bad == 0))) break;
          if (++guard > (1 << 18)) break;          // fail visibly, never hang
          __builtin_amdgcn_s_sleep(1);
          GISS(4) GISS(5) GISS(6) GISS(7)
          asm volatile("s_waitcnt vmcnt(0)");
        }
      }
      bfx8 afB[2][4];
#pragma unroll
      for (int Ks = 4; Ks < 8; ++Ks) {
        u32x4 f0 = {L[0][Ks].x, L[0][Ks].y, L[1][Ks].x, L[1][Ks].y};
        u32x4 f1 = {L2[0][Ks].x, L2[0][Ks].y, L2[1][Ks].x, L2[1][Ks].y};
        afB[0][Ks - 4] = __builtin_bit_cast(bfx8, f0);
        afB[1][Ks - 4] = __builtin_bit_cast(bfx8, f1);
      }
      // prefetch next step's x (shadowed by the B MFMA + dump/reduce phase)
      if (e < 127) {
        int tn = dir ? (126 - e) : (e + 1);
        const u16* xr = xpd + (size_t)(tn * 32 + eb) * NG + u0 + uu;
#pragma unroll
        for (int g = 0; g < 3; ++g) xn[g] = *(const u16x4*)(xr + g * U_);
      }
      __builtin_amdgcn_sched_barrier(0);
#pragma unroll
      for (int Ks = 0; Ks < 4; ++Ks)
#pragma unroll
        for (int Mt = 0; Mt < 2; ++Mt)
#pragma unroll
          for (int Nt = 0; Nt < 6; ++Nt)
            acc[Mt][Nt] = __builtin_amdgcn_mfma_f32_16x16x32_bf16(afB[Mt][Ks], wf[Nt][Ks + 4],
                                                                  acc[Mt][Nt], 0, 0, 0);
    } else {
      // e==0: rec contribution is zero; prefetch x for step 1
      int tn = dir ? 126 : 1;
      const u16* xr = xpd + (size_t)(tn * 32 + eb) * NG + u0 + uu;
#pragma unroll
      for (int g = 0; g < 3; ++g) xn[g] = *(const u16x4*)(xr + g * U_);
    }
    // dump partials: C/D layout col=lane&15, row=(lane>>4)*4+r
#pragma unroll
    for (int Mt = 0; Mt < 2; ++Mt)
#pragma unroll
      for (int Nt = 0; Nt < 6; ++Nt)
#pragma unroll
        for (int r = 0; r < 4; ++r)
          pl[wave][Mt * 16 + l4 * 4 + r][Nt * 16 + l15] = acc[Mt][Nt][r];
    BAR_LDS();                                     // LDS-only: vmem stays in flight
    // reduce K-quarters + gates; publish FIRST, then deferred y (pre-update h)
    float hold[4];
#pragma unroll
    for (int j = 0; j < 4; ++j) hold[j] = hreg[j];
#pragma unroll
    for (int j = 0; j < 4; ++j) {
      int c = uu + j;
      float rz = pl[0][eb][c]      + pl[1][eb][c]      + pl[2][eb][c]      + pl[3][eb][c];
      float rr = pl[0][eb][32 + c] + pl[1][eb][32 + c] + pl[2][eb][32 + c] + pl[3][eb][32 + c];
      float rh = pl[0][eb][64 + c] + pl[1][eb][64 + c] + pl[2][eb][64 + c] + pl[3][eb][64 + c];
      float z  = sigm(bf2f(xc[0][j]) + rz + b1[0][j]);
      float r  = sigm(bf2f(xc[1][j]) + rr + b1[1][j]);
      float hh = ftanh(bf2f(xc[2][j]) + r * (rh + b1[2][j]));
      hreg[j] = z * hreg[j] + (1.f - z) * hh;
    }
    {
      u32 p01 = (u32)f2bf(hreg[0]) | ((u32)f2bf(hreg[1]) << 16);
      u32 p23 = (u32)f2bf(hreg[2]) | ((u32)f2bf(hreg[3]) << 16);
      u32x4 sv; sv.x = p01; sv.y = p23; sv.z = (u32)(e + 1); sv.w = (u32)(e + 1);
      char* sa = hxd + rs * ROTB + soff;
      asm volatile("global_store_dwordx4 %0, %1, off sc0 sc1" :: "v"(sa), "v"(sv));
    }
    // deferred y for epoch e-1. Safe: tag-e visibility data-depends on each
    // producer's epoch-(e-1) x loads (through its hreg chain) => every WG
    // consumed XP row t(e-1) before its tag e became visible.
    if (e > 0) {
      const int tp = dir ? (128 - e) : (e - 1);
      float* yrow = (float*)(xpd + (size_t)(tp * 32 + eb) * NG);
      *(float4*)(yrow + u0 + uu) = make_float4(hold[0], hold[1], hold[2], hold[3]);
    }
    xc[0] = xn[0]; xc[1] = xn[1]; xc[2] = xn[2];
    rl = rs; rs = (rs == 2) ? 0 : rs + 1;
    BAR_LDS();                                     // protect pl; vmem in flight
  }
  // final: wait for all 32 slices' tag-128 (rot 2), then last y row + states
  {
    const char* pa = hxd + 2 * ROTB + ((lane & 31) * 8 + 7) * 512 + 31 * 16;
    int g = 0;
    while (1) {
      u32 tv = 128u;
      if (lane < 32) {
        u32x4 tvv;
        asm volatile("global_load_dwordx4 %0, %1, off sc0 sc1\n\ts_waitcnt vmcnt(0)"
                     : "=v"(tvv) : "v"(pa));
        tv = tvv.z;
      }
      if (__all((int)(tv == 128u))) break;
      if (++g > (1 << 22)) break;
      __builtin_amdgcn_s_sleep(1);
    }
    const int tl = dir ? 0 : 127;
    float* yrow = (float*)(xpd + (size_t)(tl * 32 + eb) * NG);
    *(float4*)(yrow + u0 + uu) = make_float4(hreg[0], hreg[1], hreg[2], hreg[3]);
    float* os = out + YN + (size_t)dir * (B_ * U_) + (size_t)eb * U_ + u0 + uu;
    *(float4*)os = make_float4(hreg[0], hreg[1], hreg[2], hreg[3]);
  }
}

// ---------------- M: y merge  out = yf + yb ----------------
__global__ __launch_bounds__(256) void k_merge(const u16* __restrict__ XP,
                                               float* __restrict__ out) {
  int idx = blockIdx.x * 256 + threadIdx.x;
  int u4 = (idx & 255) * 4;
  int m = idx >> 8;                            // t*32+b
  int t = m >> 5, b = m & 31;
  const float* yf = (const float*)(XP + (size_t)m * NG);
  const float* yb = (const float*)(XP + (size_t)(M_ + m) * NG);
  float4 a = *(const float4*)(yf + u4);
  float4 c = *(const float4*)(yb + u4);
  float4 o; o.x = a.x + c.x; o.y = a.y + c.y; o.z = a.z + c.z; o.w = a.w + c.w;
  *(float4*)(out + ((size_t)b * T_ + t) * U_ + u4) = o;
}

extern "C" void kernel_launch(void* const* d_in, const int* in_sizes, int n_in,
                              void* d_out, int out_size, void* d_ws, size_t ws_size,
                              hipStream_t stream) {
  const int*   tokens = (const int*)d_in[0];
  const float* emb    = (const float*)d_in[1];
  const float* kf     = (const float*)d_in[2];
  const float* rkf    = (const float*)d_in[3];
  const float* bf_    = (const float*)d_in[4];
  const float* kb     = (const float*)d_in[5];
  const float* rkb    = (const float*)d_in[6];
  const float* bb_    = (const float*)d_in[7];
  float* out = (float*)d_out;
  char* ws = (char*)d_ws;

  u16*  X  = (u16*)ws;                        // 4 MB
  u16*  WT = (u16*)(ws + 0x400000);           // 6 MB
  char* Hx = ws + 0x400000;                   // 768 KB (aliases WT; WT dead post-xproj)
  u16*  RW = (u16*)(ws + 0xA00000);           // 12 MB
  u16*  XP = (u16*)(ws + 0x1600000);          // 48 MB (y stashed in row heads)

  k_embed<<<1024, 256, 0, stream>>>(tokens, emb, X);
  k_transpose_all<<<dim3(48, 96, 2), dim3(32, 8), 0, stream>>>(kf, kb, rkf, rkb, WT, RW);
  k_xproj<<<dim3(24, 32, 2), 256, 0, stream>>>(X, WT, bf_, bb_, XP);
  hipMemsetAsync(Hx, 0, 2 * HXD, stream);
  k_gru<<<64, 256, 0, stream>>>(RW, XP, bf_, bb_, Hx, out);
  k_merge<<<4096, 256, 0, stream>>>(XP, out);
}